// Round 8
// baseline (641.705 us; speedup 1.0000x reference)
//
#include <hip/hip_runtime.h>
#include <hip/hip_fp16.h>

// GCN 3-layer, N=500000, E=8000000 — two-level binned CSR + register-pull.
//
// Algebra (aggregation commutes with linear maps):
//   L1: (A_hat @ inp) @ W1          -> 3-float aggregation of fp16 u0h (fused into buildB)
//   L2: [A_hat h1, A_hat inp] @ W2  -> 29-float pull of fp16 h1s rows (fused W2/W3)
//   L3: A_hat (h' @ W3)             -> 1-half streaming aggregation of fp16 zs
// A_hat v = dinv * (sum_nbr(dinv*v) + dinv*v_self)  (pre/post scale).
//
// Passes: split (LDS multi-split into 2048-node buckets, write-local)
//   -> buildA (1 WG/bucket: LDS hist -> scan -> rowdeg/u0/u0h)
//   -> buildB (1 WG/bucket: stream edges once: re-scatter to ebuf2 + gather
//      u0h[src] + LDS 3-float accumulate; W1/relu epilogue -> fp16 h1s)
//   -> pull2 (4 lanes/node register pull of 64B h1s rows, fused W2/relu/W3)
//   -> pull3 (1 WG/bucket: stream edges, gather fp16 zs (1MB L2), LDS scalar
//      accumulate, final scale into out)
//
// ws (floats): u0[4N] | zs(half) | rowdeg[N] | u0h[2N] | gcur[256]
//              | ebuf[256*CAPB] | ebuf2[256*CAPB] | h1s[16N]  ~= 132MB

#define CAPB       40960     // per-bucket capacity: mean 32768 (+45 sigma)
#define BSH2       11        // 2048-node coarse buckets
#define BN2        2048
#define PACK_SHIFT 19        // src < 2^19 = 524288 > N
#define PACK_MASK  0x7FFFFu
#define SPLIT_CH   4096      // edges per split block (16/thread)

typedef int v4i __attribute__((ext_vector_type(4)));

__global__ __launch_bounds__(256) void split_kernel(
    const int* __restrict__ src, const int* __restrict__ dst,
    unsigned int* __restrict__ gcur, unsigned int* __restrict__ ebuf, int E) {
    __shared__ unsigned int hist[256];
    __shared__ unsigned int gbase[256];
    int tid = threadIdx.x;
    int base = blockIdx.x * SPLIT_CH;
    hist[tid] = 0;
    __syncthreads();
    unsigned int s[16], d[16];
    if (base + SPLIT_CH <= E) {          // full chunk: int4 nontemporal loads
        const v4i* s4 = (const v4i*)(src + base);
        const v4i* d4 = (const v4i*)(dst + base);
#pragma unroll
        for (int i = 0; i < 4; i++) {
            v4i sv = __builtin_nontemporal_load(s4 + tid + 256 * i);
            v4i dv = __builtin_nontemporal_load(d4 + tid + 256 * i);
            s[4 * i + 0] = (unsigned int)sv.x; d[4 * i + 0] = (unsigned int)dv.x;
            s[4 * i + 1] = (unsigned int)sv.y; d[4 * i + 1] = (unsigned int)dv.y;
            s[4 * i + 2] = (unsigned int)sv.z; d[4 * i + 2] = (unsigned int)dv.z;
            s[4 * i + 3] = (unsigned int)sv.w; d[4 * i + 3] = (unsigned int)dv.w;
        }
#pragma unroll
        for (int i = 0; i < 16; i++) atomicAdd(&hist[d[i] >> BSH2], 1u);
    } else {                              // tail chunk: scalar with bounds
#pragma unroll
        for (int i = 0; i < 16; i++) {
            int e = base + tid + 256 * i;
            bool ok = e < E;
            s[i] = ok ? (unsigned int)src[e] : 0u;
            d[i] = ok ? (unsigned int)dst[e] : 0xFFFFFFFFu;
            if (ok) atomicAdd(&hist[d[i] >> BSH2], 1u);
        }
    }
    __syncthreads();
    unsigned int c = hist[tid];
    if (c) gbase[tid] = atomicAdd(&gcur[tid], c);
    hist[tid] = 0;                        // reuse as local cursor
    __syncthreads();
#pragma unroll
    for (int i = 0; i < 16; i++) {
        if (d[i] != 0xFFFFFFFFu) {
            unsigned int b = d[i] >> BSH2;
            unsigned int pos = gbase[b] + atomicAdd(&hist[b], 1u);
            if (pos < CAPB)
                ebuf[(size_t)b * CAPB + pos] = s[i] | ((d[i] & (BN2 - 1)) << PACK_SHIFT);
        }
    }
}

// buildA: one WG per bucket — histogram -> scan -> rowdeg/u0/u0h.
// u0 = {inp*di, di} fp32; u0h = {x0*di, x1*di, y1*di, 0} fp16 (4MB L2 table);
// rowdeg = off | deg<<16 (off < CAPB < 2^16).
__global__ __launch_bounds__(1024) void buildA_kernel(
    const unsigned int* __restrict__ gcur, const unsigned int* __restrict__ ebuf,
    const float* __restrict__ x, const float* __restrict__ y1,
    unsigned int* __restrict__ rowdeg, float4* __restrict__ u0,
    uint2* __restrict__ u0h, int N) {
    __shared__ unsigned int hist[BN2];   // 8KB
    __shared__ unsigned int aux[1024];   // 4KB scan aux
    int b = blockIdx.x, tid = threadIdx.x;
    hist[tid] = 0; hist[tid + 1024] = 0;
    unsigned int T = gcur[b]; if (T > CAPB) T = CAPB;
    const unsigned int* seg = ebuf + (size_t)b * CAPB;
    __syncthreads();
    for (unsigned int f = tid; f < T; f += 1024)
        atomicAdd(&hist[__builtin_nontemporal_load(seg + f) >> PACK_SHIFT], 1u);
    __syncthreads();
    unsigned int d0 = hist[2 * tid], d1 = hist[2 * tid + 1];
    unsigned int tsum = d0 + d1;
    aux[tid] = tsum; __syncthreads();
    for (int off = 1; off < 1024; off <<= 1) {
        unsigned int t = (tid >= off) ? aux[tid - off] : 0u;
        __syncthreads();
        aux[tid] += t;
        __syncthreads();
    }
    unsigned int base0 = aux[tid] - tsum;       // exclusive
    unsigned int base1 = base0 + d0;
#pragma unroll
    for (int k = 0; k < 2; k++) {
        int n = (b << BSH2) + 2 * tid + k;
        if (n < N) {
            unsigned int bb = k ? base1 : base0;
            unsigned int dd = k ? d1 : d0;
            rowdeg[n] = bb | (dd << 16);
            float di = rsqrtf((float)dd + 1.0f);
            float v0 = x[2 * n] * di, v1 = x[2 * n + 1] * di, v2 = y1[n] * di;
            u0[n] = make_float4(v0, v1, v2, di);
            union { __half2 h2[2]; uint2 u; } pk;
            pk.h2[0] = __floats2half2_rn(v0, v1);
            pk.h2[1] = __floats2half2_rn(v2, 0.f);
            u0h[n] = pk.u;
        }
    }
}

// buildB: one WG per bucket — single streaming loop: node-sorted re-scatter to
// ebuf2 (keeps dloc bits) + u0h[src] gather (L2) + LDS 3-float accumulate;
// then W1/relu epilogue -> fp16 h1s rows.
// h1s[n][0..28] = relu(W1^T a + b1)*di, [29..31] = a = A_hat·inp (raw).
__global__ __launch_bounds__(1024) void buildB_kernel(
    const unsigned int* __restrict__ gcur, const unsigned int* __restrict__ ebuf,
    const unsigned int* __restrict__ rowdeg, const uint2* __restrict__ u0h,
    const float4* __restrict__ u0,
    const float* __restrict__ W1, const float* __restrict__ b1,
    unsigned int* __restrict__ ebuf2, uint4* __restrict__ h1s, int N) {
    __shared__ float accs[BN2 * 3];      // 24KB, stride 3 -> all 32 banks
    __shared__ unsigned int cur2[BN2];   // 8KB running cursors (bucket-relative)
    int b = blockIdx.x, tid = threadIdx.x;
#pragma unroll
    for (int k = 0; k < 2; k++) {
        int l = 2 * tid + k;
        int n = (b << BSH2) + l;
        cur2[l] = (n < N) ? (rowdeg[n] & 0xFFFFu) : 0u;
        accs[3 * l + 0] = 0.f; accs[3 * l + 1] = 0.f; accs[3 * l + 2] = 0.f;
    }
    unsigned int T = gcur[b]; if (T > CAPB) T = CAPB;
    const unsigned int* seg = ebuf + (size_t)b * CAPB;
    unsigned int* seg2 = ebuf2 + (size_t)b * CAPB;
    __syncthreads();
    for (unsigned int f = tid; f < T; f += 1024) {
        unsigned int p = __builtin_nontemporal_load(seg + f);
        unsigned int dloc = p >> PACK_SHIFT;
        unsigned int s = p & PACK_MASK;
        unsigned int pos = atomicAdd(&cur2[dloc], 1u);
        seg2[pos] = p;                     // pull kernels mask off dloc bits
        union { uint2 u; __half2 h[2]; } g; g.u = u0h[s];
        float2 a = __half22float2(g.h[0]);
        float  c = __half2float(g.h[1].x);
        atomicAdd(&accs[3 * dloc + 0], a.x);
        atomicAdd(&accs[3 * dloc + 1], a.y);
        atomicAdd(&accs[3 * dloc + 2], c);
    }
    __syncthreads();
#pragma unroll
    for (int k = 0; k < 2; k++) {
        int l = 2 * tid + k;
        int n = (b << BSH2) + l;
        if (n >= N) continue;
        float4 u = u0[n];
        float di = u.w;
        float a0 = (accs[3 * l + 0] + u.x) * di;   // di*(sum_nbr + self)
        float a1 = (accs[3 * l + 1] + u.y) * di;
        float a2 = (accs[3 * l + 2] + u.z) * di;
        float hv[32];
#pragma unroll
        for (int q = 0; q < 29; q++) {
            float v = fmaf(a0, W1[q], fmaf(a1, W1[29 + q], fmaf(a2, W1[58 + q], b1[q])));
            hv[q] = fmaxf(v, 0.0f) * di;   // pre-scaled for next aggregation
        }
        hv[29] = a0; hv[30] = a1; hv[31] = a2;   // stash A_hat·inp
        union { __half2 h2[16]; uint4 u4[4]; } pk;
#pragma unroll
        for (int i = 0; i < 16; i++) pk.h2[i] = __floats2half2_rn(hv[2 * i], hv[2 * i + 1]);
        uint4* row = h1s + (size_t)n * 4;
#pragma unroll
        for (int t = 0; t < 4; t++) row[t] = pk.u4[t];
    }
}

__device__ __forceinline__ void unpack8(float4 r, float* o) {
    union { float4 f; __half2 h[4]; } u; u.f = r;
    float2 a = __half22float2(u.h[0]); o[0] = a.x; o[1] = a.y;
    float2 b = __half22float2(u.h[1]); o[2] = b.x; o[3] = b.y;
    float2 c = __half22float2(u.h[2]); o[4] = c.x; o[5] = c.y;
    float2 d = __half22float2(u.h[3]); o[6] = d.x; o[7] = d.y;
}

// Fused layer-2 pull + W2/relu/W3: 4 lanes/node, 64B row gather/edge,
// unroll-4 register accumulation, LDS W2, shfl_xor reduce. Writes fp16 zs + out.
__global__ __launch_bounds__(256) void pull2_kernel(
    const float4* __restrict__ h1f4, const unsigned int* __restrict__ rowdeg,
    const unsigned int* __restrict__ ebuf2, const float4* __restrict__ u0,
    const float* __restrict__ x, const float* __restrict__ y1,
    const float* __restrict__ W2, const float* __restrict__ b2,
    const float* __restrict__ W3, const float* __restrict__ b3,
    __half* __restrict__ zs, float* __restrict__ out, int N) {
    __shared__ float W2l[32 * 29];
    for (int i = threadIdx.x; i < 32 * 29; i += 256) W2l[i] = W2[i];
    int t = blockIdx.x * 256 + threadIdx.x;
    int n = t >> 2, q = t & 3;
    __syncthreads();
    if (n >= N) return;
    unsigned int rd = rowdeg[n];
    const unsigned int* lst = ebuf2 + (size_t)(n >> BSH2) * CAPB + (rd & 0xFFFFu);
    unsigned int cnt = rd >> 16;
    float acc[8] = {0.f, 0.f, 0.f, 0.f, 0.f, 0.f, 0.f, 0.f};
    unsigned int j = 0;
    for (; j + 4 <= cnt; j += 4) {        // 4 outstanding 64B row fetches
        unsigned int s0 = lst[j] & PACK_MASK;
        unsigned int s1 = lst[j + 1] & PACK_MASK;
        unsigned int s2 = lst[j + 2] & PACK_MASK;
        unsigned int s3 = lst[j + 3] & PACK_MASK;
        float4 r0 = h1f4[(size_t)s0 * 4 + q];
        float4 r1 = h1f4[(size_t)s1 * 4 + q];
        float4 r2 = h1f4[(size_t)s2 * 4 + q];
        float4 r3 = h1f4[(size_t)s3 * 4 + q];
        float f0[8], f1[8], f2[8], f3[8];
        unpack8(r0, f0); unpack8(r1, f1); unpack8(r2, f2); unpack8(r3, f3);
#pragma unroll
        for (int i = 0; i < 8; i++) acc[i] += (f0[i] + f1[i]) + (f2[i] + f3[i]);
    }
    for (; j < cnt; j++) {
        float4 r0 = h1f4[(size_t)(lst[j] & PACK_MASK) * 4 + q];
        float f0[8]; unpack8(r0, f0);
#pragma unroll
        for (int i = 0; i < 8; i++) acc[i] += f0[i];
    }
    float hs[8];
    { float4 rs = h1f4[(size_t)n * 4 + q]; unpack8(rs, hs); }
    float di = u0[n].w;
    float g[8];
#pragma unroll
    for (int i = 0; i < 8; i++) {
        int jj = 8 * q + i;
        g[i] = (jj < 29) ? (acc[i] + hs[i]) * di   // di*(sum_nbr + self)
                         : hs[i];                  // A_hat·inp (self-stash)
    }
    float p29[29];
#pragma unroll
    for (int kk = 0; kk < 29; kk++) p29[kk] = 0.f;
#pragma unroll
    for (int i = 0; i < 8; i++) {
        float gi = g[i];
        const float* wr = &W2l[(8 * q + i) * 29];
#pragma unroll
        for (int kk = 0; kk < 29; kk++) p29[kk] = fmaf(gi, wr[kk], p29[kk]);
    }
#pragma unroll
    for (int kk = 0; kk < 29; kk++) {
        p29[kk] += __shfl_xor(p29[kk], 1, 64);
        p29[kk] += __shfl_xor(p29[kk], 2, 64);
    }
    if (q == 0) {
        float z = 0.0f;
#pragma unroll
        for (int kk = 0; kk < 29; kk++)
            z = fmaf(fmaxf(p29[kk] + b2[kk], 0.0f), W3[kk], z);
        z = fmaf(x[2 * n], W3[29], z);
        z = fmaf(x[2 * n + 1], W3[30], z);
        z = fmaf(y1[n], W3[31], z);
        zs[n]  = __float2half_rn(z * di);
        out[n] = fmaf(z * di, di, b3[0]);  // self + bias; neighbor sum added by pull3
    }
}

// pull3: one WG per bucket — stream edges, gather fp16 zs (1MB L2-resident),
// LDS scalar accumulate, final scale into out.
__global__ __launch_bounds__(1024) void pull3_kernel(
    const unsigned int* __restrict__ gcur, const unsigned int* __restrict__ ebuf,
    const __half* __restrict__ zs, const float4* __restrict__ u0,
    float* __restrict__ out, int N) {
    __shared__ float accs[BN2];          // 8KB
    int b = blockIdx.x, tid = threadIdx.x;
    accs[2 * tid] = 0.f; accs[2 * tid + 1] = 0.f;
    unsigned int T = gcur[b]; if (T > CAPB) T = CAPB;
    const unsigned int* seg = ebuf + (size_t)b * CAPB;
    __syncthreads();
    for (unsigned int f = tid; f < T; f += 1024) {
        unsigned int p = __builtin_nontemporal_load(seg + f);
        float v = __half2float(zs[p & PACK_MASK]);
        atomicAdd(&accs[p >> PACK_SHIFT], v);
    }
    __syncthreads();
#pragma unroll
    for (int k = 0; k < 2; k++) {
        int l = 2 * tid + k;
        int n = (b << BSH2) + l;
        if (n < N) out[n] += accs[l] * u0[n].w;
    }
}

extern "C" void kernel_launch(void* const* d_in, const int* in_sizes, int n_in,
                              void* d_out, int out_size, void* d_ws, size_t ws_size,
                              hipStream_t stream) {
    const float* x  = (const float*)d_in[0];
    const float* y1 = (const float*)d_in[1];
    const int*   ei = (const int*)d_in[2];
    const float* W1 = (const float*)d_in[3];
    const float* b1 = (const float*)d_in[4];
    const float* W2 = (const float*)d_in[5];
    const float* b2 = (const float*)d_in[6];
    const float* W3 = (const float*)d_in[7];
    const float* b3 = (const float*)d_in[8];
    float* out = (float*)d_out;

    int N = in_sizes[1];
    int E = in_sizes[2] / 2;
    const int* src = ei;
    const int* dst = ei + E;

    size_t Ns = (size_t)N;
    int nb = (N + BN2 - 1) >> BSH2;               // 245 coarse buckets (<=256)
    size_t segtot = (size_t)256 * CAPB;           // ~10.5M entries

    float* ws = (float*)d_ws;
    float4*       u0     = (float4*)ws;                              // 4N floats
    __half*       zs     = (__half*)(ws + 4 * Ns);                   // N halves (N floats rsvd)
    unsigned int* rowdeg = (unsigned int*)(ws + 5 * Ns);             // N
    uint2*        u0h    = (uint2*)(ws + 6 * Ns);                    // 2N floats
    unsigned int* gcur   = (unsigned int*)(ws + 8 * Ns);             // 256
    unsigned int* ebuf   = gcur + 256;                               // segtot
    unsigned int* ebuf2  = ebuf + segtot;                            // segtot
    uint4*        h1s    = (uint4*)(ebuf2 + segtot);                 // 16N floats (fp16 rows)

    hipMemsetAsync(gcur, 0, 256 * sizeof(unsigned int), stream);

    const int gS = (E + SPLIT_CH - 1) / SPLIT_CH;
    const int g4 = (4 * N + 255) / 256;
    split_kernel <<<gS, 256, 0, stream>>>(src, dst, gcur, ebuf, E);
    buildA_kernel<<<nb, 1024, 0, stream>>>(gcur, ebuf, x, y1, rowdeg, u0, u0h, N);
    buildB_kernel<<<nb, 1024, 0, stream>>>(gcur, ebuf, rowdeg, u0h, u0, W1, b1,
                                           ebuf2, h1s, N);
    pull2_kernel <<<g4, 256, 0, stream>>>((const float4*)h1s, rowdeg, ebuf2, u0,
                                          x, y1, W2, b2, W3, b3, zs, out, N);
    pull3_kernel <<<nb, 1024, 0, stream>>>(gcur, ebuf, zs, u0, out, N);
}

// Round 9
// 526.808 us; speedup vs baseline: 1.2181x; 1.2181x over previous
//
#include <hip/hip_runtime.h>
#include <hip/hip_fp16.h>

// GCN 3-layer, N=500000, E=8000000 — two-level binned CSR + register-pull.
//
// Algebra (aggregation commutes with linear maps):
//   L1: (A_hat @ inp) @ W1          -> 3-float pull of fp16 u0h (4MB, L2-resident)
//   L2: [A_hat h1, A_hat inp] @ W2  -> 29-float pull of fp16 h1s rows (fused W2/W3)
//   L3: A_hat (h' @ W3)             -> 1-half pull of fp16 zs (1MB, L2-resident)
// A_hat v = dinv * (sum_nbr(dinv*v) + dinv*v_self)  (pre/post scale).
//
// Passes: split (LDS multi-split into 2048-node buckets, write-local)
//   -> build (1 WG/bucket: hist -> scan -> rowdeg/u0/u0h; then node-sort via
//      IN-LDS scatter in 4 node-quarter passes, flushed sequentially to ebuf2
//      -> full-line writes, no partial-line writeback amplification)
//   -> layer1 (2 lanes/node pull of u0h + W1/relu -> fp16 h1s rows)
//   -> pull2 (4 lanes/node register pull of 64B h1s rows, fused W2/relu/W3)
//   -> pull3 (1 thread/node pull of fp16 zs + final scale)
//
// ws (floats): u0[4N] | zs(half) | rowdeg[N] | u0h[2N] | gcur[256]
//              | ebuf[256*CAPB] | ebuf2[256*CAPB] | h1s[16N]  ~= 132MB

#define CAPB       40960     // per-bucket capacity: mean 32768 (+45 sigma)
#define BSH2       11        // 2048-node coarse buckets
#define BN2        2048
#define PACK_SHIFT 19        // src < 2^19 = 524288 > N
#define PACK_MASK  0x7FFFFu
#define SPLIT_CH   4096      // edges per split block (16/thread)
#define CAPQ       9216      // LDS quarter buffer: mean 8192, +11 sigma

typedef int v4i __attribute__((ext_vector_type(4)));

__global__ __launch_bounds__(256) void split_kernel(
    const int* __restrict__ src, const int* __restrict__ dst,
    unsigned int* __restrict__ gcur, unsigned int* __restrict__ ebuf, int E) {
    __shared__ unsigned int hist[256];
    __shared__ unsigned int gbase[256];
    int tid = threadIdx.x;
    int base = blockIdx.x * SPLIT_CH;
    hist[tid] = 0;
    __syncthreads();
    unsigned int s[16], d[16];
    if (base + SPLIT_CH <= E) {          // full chunk: int4 nontemporal loads
        const v4i* s4 = (const v4i*)(src + base);
        const v4i* d4 = (const v4i*)(dst + base);
#pragma unroll
        for (int i = 0; i < 4; i++) {
            v4i sv = __builtin_nontemporal_load(s4 + tid + 256 * i);
            v4i dv = __builtin_nontemporal_load(d4 + tid + 256 * i);
            s[4 * i + 0] = (unsigned int)sv.x; d[4 * i + 0] = (unsigned int)dv.x;
            s[4 * i + 1] = (unsigned int)sv.y; d[4 * i + 1] = (unsigned int)dv.y;
            s[4 * i + 2] = (unsigned int)sv.z; d[4 * i + 2] = (unsigned int)dv.z;
            s[4 * i + 3] = (unsigned int)sv.w; d[4 * i + 3] = (unsigned int)dv.w;
        }
#pragma unroll
        for (int i = 0; i < 16; i++) atomicAdd(&hist[d[i] >> BSH2], 1u);
    } else {                              // tail chunk: scalar with bounds
#pragma unroll
        for (int i = 0; i < 16; i++) {
            int e = base + tid + 256 * i;
            bool ok = e < E;
            s[i] = ok ? (unsigned int)src[e] : 0u;
            d[i] = ok ? (unsigned int)dst[e] : 0xFFFFFFFFu;
            if (ok) atomicAdd(&hist[d[i] >> BSH2], 1u);
        }
    }
    __syncthreads();
    unsigned int c = hist[tid];
    if (c) gbase[tid] = atomicAdd(&gcur[tid], c);
    hist[tid] = 0;                        // reuse as local cursor
    __syncthreads();
#pragma unroll
    for (int i = 0; i < 16; i++) {
        if (d[i] != 0xFFFFFFFFu) {
            unsigned int b = d[i] >> BSH2;
            unsigned int pos = gbase[b] + atomicAdd(&hist[b], 1u);
            if (pos < CAPB)
                ebuf[(size_t)b * CAPB + pos] = s[i] | ((d[i] & (BN2 - 1)) << PACK_SHIFT);
        }
    }
}

// build: one WG per bucket.
//  1) LDS histogram over the bucket's edges
//  2) Hillis-Steele scan -> per-node bases; epilogue rowdeg/u0/u0h
//  3) node-sort: 4 node-quarter passes; scatter into 36KB LDS buffer, flush
//     sequentially to ebuf2 (full-line coalesced writes, clean 19-bit src).
__global__ __launch_bounds__(1024) void build_kernel(
    const unsigned int* __restrict__ gcur, const unsigned int* __restrict__ ebuf,
    const float* __restrict__ x, const float* __restrict__ y1,
    unsigned int* __restrict__ rowdeg, float4* __restrict__ u0,
    uint2* __restrict__ u0h, unsigned int* __restrict__ ebuf2, int N) {
    __shared__ unsigned int hist[BN2];   // 8KB: counts -> bases -> cursors
    __shared__ unsigned int aux[1024];   // 4KB scan aux
    __shared__ unsigned int qoff[5];     // quarter boundaries
    __shared__ unsigned int dest[CAPQ];  // 36KB quarter staging
    int b = blockIdx.x, tid = threadIdx.x;
    hist[tid] = 0; hist[tid + 1024] = 0;
    unsigned int T = gcur[b]; if (T > CAPB) T = CAPB;
    const unsigned int* seg = ebuf + (size_t)b * CAPB;
    unsigned int* seg2 = ebuf2 + (size_t)b * CAPB;
    __syncthreads();
    for (unsigned int f = tid; f < T; f += 1024)
        atomicAdd(&hist[seg[f] >> PACK_SHIFT], 1u);
    __syncthreads();
    unsigned int d0 = hist[2 * tid], d1 = hist[2 * tid + 1];
    unsigned int tsum = d0 + d1;
    aux[tid] = tsum; __syncthreads();
    for (int off = 1; off < 1024; off <<= 1) {
        unsigned int t = (tid >= off) ? aux[tid - off] : 0u;
        __syncthreads();
        aux[tid] += t;
        __syncthreads();
    }
    unsigned int base0 = aux[tid] - tsum;       // exclusive
    unsigned int base1 = base0 + d0;
    hist[2 * tid] = base0; hist[2 * tid + 1] = base1;   // running cursors
    if ((tid & 255) == 0) qoff[tid >> 8] = base0;       // node 512*q boundary
    if (tid == 0) qoff[4] = T;
#pragma unroll
    for (int k = 0; k < 2; k++) {
        int n = (b << BSH2) + 2 * tid + k;
        if (n < N) {
            unsigned int bb = k ? base1 : base0;
            unsigned int dd = k ? d1 : d0;
            rowdeg[n] = bb | (dd << 16);
            float di = rsqrtf((float)dd + 1.0f);
            float v0 = x[2 * n] * di, v1 = x[2 * n + 1] * di, v2 = y1[n] * di;
            u0[n] = make_float4(v0, v1, v2, di);
            union { __half2 h2[2]; uint2 u; } pk;
            pk.h2[0] = __floats2half2_rn(v0, v1);
            pk.h2[1] = __floats2half2_rn(v2, 0.f);
            u0h[n] = pk.u;
        }
    }
    __syncthreads();
    for (unsigned int q = 0; q < 4; q++) {
        unsigned int qs = qoff[q], qe = qoff[q + 1];
        for (unsigned int f = tid; f < T; f += 1024) {
            unsigned int p = seg[f];
            unsigned int dloc = p >> PACK_SHIFT;
            if ((dloc >> 9) == q) {
                unsigned int pos = atomicAdd(&hist[dloc], 1u);   // absolute
                unsigned int loc = pos - qs;
                if (loc < CAPQ) dest[loc] = p & PACK_MASK;
                else            seg2[pos] = p & PACK_MASK;       // rare overflow
            }
        }
        __syncthreads();
        unsigned int qcnt = qe - qs; if (qcnt > CAPQ) qcnt = CAPQ;
        for (unsigned int i = tid; i < qcnt; i += 1024)
            seg2[qs + i] = dest[i];        // sequential full-line flush
        __syncthreads();
    }
}

// Layer-1 pull: 2 lanes/node gather fp16 u0h (4MB L2-resident), shfl reduce,
// each lane computes 16 of the 32 outputs -> fp16 h1s rows.
// h1s[n][0..28] = relu(W1^T a + b1)*di, [29..31] = a = A_hat·inp (raw).
__global__ __launch_bounds__(256) void layer1_kernel(
    const float4* __restrict__ u0, const uint2* __restrict__ u0h,
    const unsigned int* __restrict__ rowdeg, const unsigned int* __restrict__ ebuf2,
    const float* __restrict__ W1, const float* __restrict__ b1,
    uint4* __restrict__ h1s, int N) {
    int t = blockIdx.x * 256 + threadIdx.x;
    int n = t >> 1, q = t & 1;
    if (n >= N) return;
    unsigned int rd = rowdeg[n];
    const unsigned int* lst = ebuf2 + (size_t)(n >> BSH2) * CAPB + (rd & 0xFFFFu);
    unsigned int cnt = rd >> 16;
    unsigned int half = cnt >> 1;
    unsigned int j0 = q ? half : 0, j1 = q ? cnt : half;
    float4 u = u0[n];
    float sx = q ? 0.f : u.x, sy = q ? 0.f : u.y, sz = q ? 0.f : u.z;  // self on lane0
    unsigned int j = j0;
    for (; j + 4 <= j1; j += 4) {
        unsigned int i0 = lst[j], i1 = lst[j + 1], i2 = lst[j + 2], i3 = lst[j + 3];
        union { uint2 u; __half2 h[2]; } g0, g1, g2, g3;
        g0.u = u0h[i0]; g1.u = u0h[i1]; g2.u = u0h[i2]; g3.u = u0h[i3];
        float2 a0 = __half22float2(g0.h[0]), c0 = __half22float2(g0.h[1]);
        float2 a1 = __half22float2(g1.h[0]), c1 = __half22float2(g1.h[1]);
        float2 a2 = __half22float2(g2.h[0]), c2 = __half22float2(g2.h[1]);
        float2 a3 = __half22float2(g3.h[0]), c3 = __half22float2(g3.h[1]);
        sx += (a0.x + a1.x) + (a2.x + a3.x);
        sy += (a0.y + a1.y) + (a2.y + a3.y);
        sz += (c0.x + c1.x) + (c2.x + c3.x);
    }
    for (; j < j1; j++) {
        union { uint2 u; __half2 h[2]; } g; g.u = u0h[lst[j]];
        float2 a = __half22float2(g.h[0]);
        sx += a.x; sy += a.y; sz += __half2float(g.h[1].x);
    }
    sx += __shfl_xor(sx, 1, 64);
    sy += __shfl_xor(sy, 1, 64);
    sz += __shfl_xor(sz, 1, 64);
    float di = u.w;
    float a0 = sx * di, a1 = sy * di, a2 = sz * di;
    float hv[16];
#pragma unroll
    for (int i = 0; i < 16; i++) {
        int k = 16 * q + i;
        if (k < 29) {
            float v = fmaf(a0, W1[k], fmaf(a1, W1[29 + k], fmaf(a2, W1[58 + k], b1[k])));
            hv[i] = fmaxf(v, 0.0f) * di;   // pre-scaled for next aggregation
        } else {
            hv[i] = (k == 29) ? a0 : (k == 30) ? a1 : a2;   // stash A_hat·inp
        }
    }
    union { __half2 h2[8]; uint4 u4[2]; } pk;
#pragma unroll
    for (int i = 0; i < 8; i++) pk.h2[i] = __floats2half2_rn(hv[2 * i], hv[2 * i + 1]);
    uint4* row = h1s + (size_t)n * 4 + 2 * q;
    row[0] = pk.u4[0];
    row[1] = pk.u4[1];
}

__device__ __forceinline__ void unpack8(float4 r, float* o) {
    union { float4 f; __half2 h[4]; } u; u.f = r;
    float2 a = __half22float2(u.h[0]); o[0] = a.x; o[1] = a.y;
    float2 b = __half22float2(u.h[1]); o[2] = b.x; o[3] = b.y;
    float2 c = __half22float2(u.h[2]); o[4] = c.x; o[5] = c.y;
    float2 d = __half22float2(u.h[3]); o[6] = d.x; o[7] = d.y;
}

// Fused layer-2 pull + W2/relu/W3: 4 lanes/node, 64B row gather/edge,
// unroll-4 register accumulation, LDS W2, shfl_xor reduce. Writes fp16 zs + out.
__global__ __launch_bounds__(256) void pull2_kernel(
    const float4* __restrict__ h1f4, const unsigned int* __restrict__ rowdeg,
    const unsigned int* __restrict__ ebuf2, const float4* __restrict__ u0,
    const float* __restrict__ x, const float* __restrict__ y1,
    const float* __restrict__ W2, const float* __restrict__ b2,
    const float* __restrict__ W3, const float* __restrict__ b3,
    __half* __restrict__ zs, float* __restrict__ out, int N) {
    __shared__ float W2l[32 * 29];
    for (int i = threadIdx.x; i < 32 * 29; i += 256) W2l[i] = W2[i];
    int t = blockIdx.x * 256 + threadIdx.x;
    int n = t >> 2, q = t & 3;
    __syncthreads();
    if (n >= N) return;
    unsigned int rd = rowdeg[n];
    const unsigned int* lst = ebuf2 + (size_t)(n >> BSH2) * CAPB + (rd & 0xFFFFu);
    unsigned int cnt = rd >> 16;
    float acc[8] = {0.f, 0.f, 0.f, 0.f, 0.f, 0.f, 0.f, 0.f};
    unsigned int j = 0;
    for (; j + 4 <= cnt; j += 4) {        // 4 outstanding 64B row fetches
        unsigned int s0 = lst[j], s1 = lst[j + 1], s2 = lst[j + 2], s3 = lst[j + 3];
        float4 r0 = h1f4[(size_t)s0 * 4 + q];
        float4 r1 = h1f4[(size_t)s1 * 4 + q];
        float4 r2 = h1f4[(size_t)s2 * 4 + q];
        float4 r3 = h1f4[(size_t)s3 * 4 + q];
        float f0[8], f1[8], f2[8], f3[8];
        unpack8(r0, f0); unpack8(r1, f1); unpack8(r2, f2); unpack8(r3, f3);
#pragma unroll
        for (int i = 0; i < 8; i++) acc[i] += (f0[i] + f1[i]) + (f2[i] + f3[i]);
    }
    for (; j < cnt; j++) {
        float4 r0 = h1f4[(size_t)lst[j] * 4 + q];
        float f0[8]; unpack8(r0, f0);
#pragma unroll
        for (int i = 0; i < 8; i++) acc[i] += f0[i];
    }
    float hs[8];
    { float4 rs = h1f4[(size_t)n * 4 + q]; unpack8(rs, hs); }
    float di = u0[n].w;
    float g[8];
#pragma unroll
    for (int i = 0; i < 8; i++) {
        int jj = 8 * q + i;
        g[i] = (jj < 29) ? (acc[i] + hs[i]) * di   // di*(sum_nbr + self)
                         : hs[i];                  // A_hat·inp (self-stash)
    }
    float p29[29];
#pragma unroll
    for (int kk = 0; kk < 29; kk++) p29[kk] = 0.f;
#pragma unroll
    for (int i = 0; i < 8; i++) {
        float gi = g[i];
        const float* wr = &W2l[(8 * q + i) * 29];
#pragma unroll
        for (int kk = 0; kk < 29; kk++) p29[kk] = fmaf(gi, wr[kk], p29[kk]);
    }
#pragma unroll
    for (int kk = 0; kk < 29; kk++) {
        p29[kk] += __shfl_xor(p29[kk], 1, 64);
        p29[kk] += __shfl_xor(p29[kk], 2, 64);
    }
    if (q == 0) {
        float z = 0.0f;
#pragma unroll
        for (int kk = 0; kk < 29; kk++)
            z = fmaf(fmaxf(p29[kk] + b2[kk], 0.0f), W3[kk], z);
        z = fmaf(x[2 * n], W3[29], z);
        z = fmaf(x[2 * n + 1], W3[30], z);
        z = fmaf(y1[n], W3[31], z);
        zs[n]  = __float2half_rn(z * di);
        out[n] = fmaf(z * di, di, b3[0]);  // self + bias; neighbor sum added by pull3
    }
}

// Layer-3 pull (2B fp16 gathers from 1MB L2-resident zs) + final scale.
__global__ void pull3_kernel(const __half* __restrict__ zs, const float4* __restrict__ u0,
                             const unsigned int* __restrict__ rowdeg,
                             const unsigned int* __restrict__ ebuf2,
                             float* __restrict__ out, int N) {
    int n = blockIdx.x * blockDim.x + threadIdx.x;
    if (n >= N) return;
    unsigned int rd = rowdeg[n];
    const unsigned int* lst = ebuf2 + (size_t)(n >> BSH2) * CAPB + (rd & 0xFFFFu);
    unsigned int cnt = rd >> 16;
    float s = 0.f;
    unsigned int j = 0;
    for (; j + 4 <= cnt; j += 4) {
        unsigned int i0 = __builtin_nontemporal_load(lst + j);
        unsigned int i1 = __builtin_nontemporal_load(lst + j + 1);
        unsigned int i2 = __builtin_nontemporal_load(lst + j + 2);
        unsigned int i3 = __builtin_nontemporal_load(lst + j + 3);
        s += (__half2float(zs[i0]) + __half2float(zs[i1]))
           + (__half2float(zs[i2]) + __half2float(zs[i3]));
    }
    for (; j < cnt; j++) s += __half2float(zs[lst[j]]);
    out[n] += s * u0[n].w;
}

extern "C" void kernel_launch(void* const* d_in, const int* in_sizes, int n_in,
                              void* d_out, int out_size, void* d_ws, size_t ws_size,
                              hipStream_t stream) {
    const float* x  = (const float*)d_in[0];
    const float* y1 = (const float*)d_in[1];
    const int*   ei = (const int*)d_in[2];
    const float* W1 = (const float*)d_in[3];
    const float* b1 = (const float*)d_in[4];
    const float* W2 = (const float*)d_in[5];
    const float* b2 = (const float*)d_in[6];
    const float* W3 = (const float*)d_in[7];
    const float* b3 = (const float*)d_in[8];
    float* out = (float*)d_out;

    int N = in_sizes[1];
    int E = in_sizes[2] / 2;
    const int* src = ei;
    const int* dst = ei + E;

    size_t Ns = (size_t)N;
    int nb = (N + BN2 - 1) >> BSH2;               // 245 coarse buckets (<=256)
    size_t segtot = (size_t)256 * CAPB;           // ~10.5M entries

    float* ws = (float*)d_ws;
    float4*       u0     = (float4*)ws;                              // 4N floats
    __half*       zs     = (__half*)(ws + 4 * Ns);                   // N halves (N floats rsvd)
    unsigned int* rowdeg = (unsigned int*)(ws + 5 * Ns);             // N
    uint2*        u0h    = (uint2*)(ws + 6 * Ns);                    // 2N floats
    unsigned int* gcur   = (unsigned int*)(ws + 8 * Ns);             // 256
    unsigned int* ebuf   = gcur + 256;                               // segtot
    unsigned int* ebuf2  = ebuf + segtot;                            // segtot
    uint4*        h1s    = (uint4*)(ebuf2 + segtot);                 // 16N floats (fp16 rows)

    hipMemsetAsync(gcur, 0, 256 * sizeof(unsigned int), stream);

    const int gS = (E + SPLIT_CH - 1) / SPLIT_CH;
    const int gN = (N + 255) / 256;
    const int g2 = (2 * N + 255) / 256;
    const int g4 = (4 * N + 255) / 256;
    split_kernel <<<gS, 256, 0, stream>>>(src, dst, gcur, ebuf, E);
    build_kernel <<<nb, 1024, 0, stream>>>(gcur, ebuf, x, y1, rowdeg, u0, u0h, ebuf2, N);
    layer1_kernel<<<g2, 256, 0, stream>>>(u0, u0h, rowdeg, ebuf2, W1, b1, h1s, N);
    pull2_kernel <<<g4, 256, 0, stream>>>((const float4*)h1s, rowdeg, ebuf2, u0,
                                          x, y1, W2, b2, W3, b3, zs, out, N);
    pull3_kernel <<<gN, 256, 0, stream>>>(zs, u0, rowdeg, ebuf2, out, N);
}